// Round 16
// baseline (686.026 us; speedup 1.0000x reference)
//
#include <hip/hip_runtime.h>
#include <hip/hip_bf16.h>
#include <hip/hip_cooperative_groups.h>

namespace cg = cooperative_groups;

// CrystalHypergraphConv — MI355X implementation.
//
// z[e] = A[idx0[e]] + C[idx1[e]];  A [N,256] bf16-packed; C [NHE,256]
// fp8-e4m3-packed. Lane l owns channels {2l,2l+1,128+2l,129+2l}.
//
// R31 -> R32: cooperative launch-boundary collapse (11 ops -> 6 launches).
//  - k_front (coop): zero-scratch -> sync -> prepw+counts -> sync ->
//    scans+scatterpos. Replaces memset + k_pre + k_scan.
//  - k_tail (coop): bn2stats -> sync -> h2pool -> sync -> head.
//    Replaces 3 tail launches.
//  k_stats/k_aggr NOT fused (R26: coop co-residency cap kills k_aggr's
//  needed over-subscription). Edge passes unchanged at the confirmed
//  ~1.4TB/s pattern ceiling.

#define EPS_BN 1e-5f
#define LOG2E 1.4426950408889634f
#define LN2   0.6931471805599453f

#define BIN_SH 8
#define BIN_CHUNK 4096

typedef __attribute__((ext_vector_type(8))) short bf16x8;
typedef __attribute__((ext_vector_type(4))) float f32x4;
typedef __attribute__((ext_vector_type(2))) float f32x2;

__device__ __forceinline__ float fexp2(float x) {
#if __has_builtin(__builtin_amdgcn_exp2f)
    return __builtin_amdgcn_exp2f(x);
#else
    return __expf(x * LN2);
#endif
}
__device__ __forceinline__ float flog2(float x) {
#if __has_builtin(__builtin_amdgcn_logf)
    return __builtin_amdgcn_logf(x);
#else
    return __logf(x) * LOG2E;
#endif
}
__device__ __forceinline__ float softplus_fast(float x) {
    return LN2 * flog2(1.f + fexp2(x * LOG2E));
}

__device__ __forceinline__ f32x2 pk_fma2(f32x2 a, f32x2 b, f32x2 c) {
#if __has_builtin(__builtin_elementwise_fma)
    return __builtin_elementwise_fma(a, b, c);
#else
    return (f32x2){fmaf(a.x, b.x, c.x), fmaf(a.y, b.y, c.y)};
#endif
}

__device__ __forceinline__ unsigned short f2bf(float f) {
    unsigned u = __float_as_uint(f);
    unsigned r = (u + 0x7fffu + ((u >> 16) & 1u)) >> 16;   // RNE
    return (unsigned short)r;
}
__device__ __forceinline__ float bflo(unsigned u) { return __uint_as_float(u << 16); }
__device__ __forceinline__ float bfhi(unsigned u) { return __uint_as_float(u & 0xffff0000u); }
__device__ __forceinline__ float bfu16(unsigned short v) { return __uint_as_float(((unsigned)v) << 16); }
__device__ __forceinline__ unsigned pack2bf(float x, float y) {
    return (unsigned)f2bf(x) | ((unsigned)f2bf(y) << 16);
}

// ---- fp8 e4m3 encode/decode (OCP; HW path on gfx950) ----
#if __has_builtin(__builtin_amdgcn_cvt_pk_f32_fp8) && __has_builtin(__builtin_amdgcn_cvt_pk_fp8_f32)
#define HW_FP8 1
#else
#define HW_FP8 0
#endif

__device__ __forceinline__ unsigned char f2fp8(float f) {
#if HW_FP8
    int r = __builtin_amdgcn_cvt_pk_fp8_f32(f, f, 0, false);
    return (unsigned char)(r & 0xff);
#else
    unsigned u = __float_as_uint(f);
    unsigned s = (u >> 24) & 0x80u;
    float af = fabsf(f);
    if (!(af >= 0.015625f)) {
        int m = (int)rintf(af * 512.f);
        if (m > 7) m = 7;
        return (unsigned char)(s | (unsigned)m);
    }
    if (af > 448.f) return (unsigned char)(s | 0x7e);
    unsigned au = __float_as_uint(af);
    unsigned r = au + 0x7ffffu + ((au >> 20) & 1u);
    int e8 = (int)(r >> 23) - 120;
    unsigned m = (r >> 20) & 7u;
    if (e8 > 15 || (e8 == 15 && m == 7)) return (unsigned char)(s | 0x7e);
    return (unsigned char)(s | ((unsigned)e8 << 3) | m);
#endif
}

// decode packed word -> lo pair (bytes 0,1 = f channels), hi pair (bytes 2,3 = c channels)
__device__ __forceinline__ void fp8pair(unsigned p, f32x2& lo, f32x2& hi) {
#if HW_FP8
    lo = __builtin_amdgcn_cvt_pk_f32_fp8((int)p, false);
    hi = __builtin_amdgcn_cvt_pk_f32_fp8((int)p, true);
#else
    auto dec = [](unsigned byte) -> float {
        unsigned s = (byte & 0x80u) << 24;
        unsigned em = byte & 0x7fu;
        float nrm = __uint_as_float(s | ((em << 20) + 0x3C000000u));
        float sub = __uint_as_float(s | 0x3F800000u) * (float)em * 0.001953125f;
        return (em >= 8) ? nrm : sub;
    };
    lo = (f32x2){dec(p & 0xff), dec((p >> 8) & 0xff)};
    hi = (f32x2){dec((p >> 16) & 0xff), dec(p >> 24)};
#endif
}

__device__ __forceinline__ int perm256(int j) {
    return (j < 128) ? ((j >> 1) * 4 + (j & 1)) : (((j - 128) >> 1) * 4 + 2 + (j & 1));
}

// ---------------- k_front (cooperative): zero -> prepw+counts -> scans+scatterpos ----------------
__global__ __launch_bounds__(256) void k_front(
    const float* __restrict__ ew, const float* __restrict__ bw, const float* __restrict__ lw,
    unsigned short* __restrict__ embB, unsigned short* __restrict__ bembB,
    unsigned short* __restrict__ waB, unsigned short* __restrict__ wcB,
    const int* __restrict__ idx0, const int* __restrict__ batch,
    int* __restrict__ bsum, int* __restrict__ gcount,
    float* __restrict__ zbase, int zwords,
    int* __restrict__ boff, int* __restrict__ gptr, int* __restrict__ gfill,
    int* __restrict__ pos_of,
    int E, int N, int NB, int EB, int GB)
{
    cg::grid_group grid = cg::this_grid();
    __shared__ int s[256];
    __shared__ int lg[128];
    __shared__ int lhist[256];
    __shared__ int lbat[128];
    const int t = threadIdx.x;
    const int bid = blockIdx.x;

    // ---- phase 0: zero the scratch region ----
    for (int i = bid * 256 + t; i < zwords; i += gridDim.x * 256)
        ((int*)zbase)[i] = 0;
    grid.sync();

    // ---- phase 1: prepw (bid<320) + counts (320 <= bid < 320+EB) ----
    if (bid >= 320 && bid < 320 + EB) {
        const int cb = bid - 320;
        lhist[t] = 0;
        if (t < 128) lbat[t] = 0;
        __syncthreads();
        const int e0 = cb * BIN_CHUNK;
        const int ecnt = min(E - e0, BIN_CHUNK);
        for (int i = t; i < ecnt; i += 256)
            atomicAdd(&lhist[idx0[e0 + i] >> BIN_SH], 1);
        const int n0 = cb * BIN_CHUNK;
        const int ncnt = min(N - n0, BIN_CHUNK);
        for (int i = t; i < ncnt; i += 256)
            atomicAdd(&lbat[batch[n0 + i]], 1);
        __syncthreads();
        if (t < NB && lhist[t]) atomicAdd(&bsum[t], lhist[t]);
        if (t < 128 && lbat[t]) atomicAdd(&gcount[t], lbat[t]);
    } else if (bid < 320) {
        int i = bid * 256 + t;
        if (i < 81920) {
            unsigned short* dst;
            int f, NKC, CT, mode;
            if (i < 12288)      { dst = embB;  f = i;         NKC = 3; CT = 2; mode = 0; }
            else if (i < 20480) { dst = bembB; f = i - 12288; NKC = 2; CT = 2; mode = 1; }
            else if (i < 53248) { dst = waB;   f = i - 20480; NKC = 4; CT = 4; mode = 2; }
            else                { dst = wcB;   f = i - 53248; NKC = 4; CT = 4; mode = 3; }
            int j = f & 7, l = (f >> 3) & 63;
            int r2 = f >> 9;
            int c = r2 % CT;
            int r3 = r2 / CT;
            int kc = r3 % NKC, w = r3 / NKC;
            int k = kc * 32 + ((l >> 4) & 3) * 8 + j;
            int n = (w * CT + c) * 16 + (l & 15);
            float v;
            if (mode == 0)      v = (k < 92) ? ew[k * 128 + n] : 0.f;
            else if (mode == 1) v = (k < 40) ? bw[k * 128 + n] : 0.f;
            else if (mode == 2) v = lw[k * 256 + n] + lw[(k + 256) * 256 + n];
            else                v = lw[(k + 128) * 256 + n];
            dst[f] = f2bf(v);
        }
    }
    grid.sync();

    // ---- phase 2: scans (bid 0) + scatterpos (bid 1..GB) ----
    if (bid == 0) {
        int v = (t < NB) ? bsum[t] : 0;
        s[t] = v;
        __syncthreads();
#pragma unroll
        for (int ofs = 1; ofs < 256; ofs <<= 1) {
            int u = (t >= ofs) ? s[t - ofs] : 0;
            __syncthreads();
            s[t] += u;
            __syncthreads();
        }
        if (t < NB) boff[t] = s[t] - v;              // exclusive bucket offsets
        if (t == NB - 1) boff[NB] = s[t];            // total = E
        __syncthreads();
        int gv = (t < 128) ? gcount[t] : 0;
        s[t] = gv;
        __syncthreads();
#pragma unroll
        for (int ofs = 1; ofs < 128; ofs <<= 1) {
            int u = (t >= ofs && t < 128) ? s[t - ofs] : 0;
            __syncthreads();
            if (t < 128) s[t] += u;
            __syncthreads();
        }
        if (t < 128) gptr[t + 1] = s[t];
        if (t == 0) gptr[0] = 0;
    } else if (bid <= GB) {
        int gv = (t < 128) ? gcount[t] : 0;
        s[t] = gv;
        __syncthreads();
#pragma unroll
        for (int ofs = 1; ofs < 128; ofs <<= 1) {
            int u = (t >= ofs && t < 128) ? s[t - ofs] : 0;
            __syncthreads();
            if (t < 128) s[t] += u;
            __syncthreads();
        }
        if (t < 128) lg[t] = s[t] - gv;              // exclusive gptr
        __syncthreads();
        int i = (bid - 1) * 256 + t;
        if (i < N) {
            int g = batch[i];
            pos_of[i] = lg[g] + atomicAdd(&gfill[g], 1);
        }
    }
}

// ---------------- GEMM body (device) ----------------
// OMODE2: 1 = bf16-packed A + bf16 h out (h at pos_of[row]); 2 = fp8-packed C out
template<int KIN, int NKC1, int OMODE2>
__device__ __forceinline__ void gemm_body(
    char* smem, int blk,
    const float* __restrict__ in, const unsigned short* __restrict__ B1, const float* __restrict__ bias1,
    const unsigned short* __restrict__ B2, const float* __restrict__ bias2,
    unsigned short* __restrict__ hout, void* __restrict__ out2, int M,
    const int* __restrict__ pos_of)
{
    const int r0 = blk * 32;
    const int t = threadIdx.x;
    const int w = t >> 6;
    const int l = t & 63;
    const int m = l & 15, q = l >> 4;

    unsigned short* als = (unsigned short*)smem;                  // 32*NKC1*32 shorts
    unsigned short* hls = als + 32 * NKC1 * 32;                   // 32*136 shorts

    const int KP = NKC1 * 32;
    for (int i = t; i < 32 * KP; i += 256) {
        int r = i / KP, k = i - r * KP;
        int gr = r0 + r;
        float v = (gr < M && k < KIN) ? in[(size_t)gr * KIN + k] : 0.f;
        int idx = (((r >> 4) * NKC1 + (k >> 5)) * 64 + ((k >> 3) & 3) * 16 + (r & 15)) * 8 + (k & 7);
        als[idx] = f2bf(v);
    }
    bf16x8 b1[NKC1][2];
    const bf16x8* B1f = (const bf16x8*)B1;
#pragma unroll
    for (int kc = 0; kc < NKC1; kc++)
#pragma unroll
        for (int c = 0; c < 2; c++)
            b1[kc][c] = B1f[((w * NKC1 + kc) * 2 + c) * 64 + l];
    __syncthreads();

    f32x4 acc1[2][2];
#pragma unroll
    for (int c = 0; c < 2; c++) { acc1[c][0] = (f32x4){0.f,0.f,0.f,0.f}; acc1[c][1] = (f32x4){0.f,0.f,0.f,0.f}; }
    const bf16x8* af = (const bf16x8*)als;
#pragma unroll
    for (int kc = 0; kc < NKC1; kc++) {
        bf16x8 a0 = af[kc * 64 + l];
        bf16x8 a1 = af[(NKC1 + kc) * 64 + l];
#pragma unroll
        for (int c = 0; c < 2; c++) {
            acc1[c][0] = __builtin_amdgcn_mfma_f32_16x16x32_bf16(a0, b1[kc][c], acc1[c][0], 0, 0, 0);
            acc1[c][1] = __builtin_amdgcn_mfma_f32_16x16x32_bf16(a1, b1[kc][c], acc1[c][1], 0, 0, 0);
        }
    }
#pragma unroll
    for (int c = 0; c < 2; c++) {
        int n1 = (w * 2 + c) * 16 + m;
        float bv = bias1[n1];
#pragma unroll
        for (int hh = 0; hh < 2; hh++) {
#pragma unroll
            for (int r = 0; r < 4; r++) {
                int row = hh * 16 + q * 4 + r;
                float val = acc1[c][hh][r] + bv;
                unsigned short bf = f2bf(val);
                hls[row * 136 + n1] = bf;
                if (OMODE2 == 1 && r0 + row < M)
                    hout[(size_t)pos_of[r0 + row] * 128 + n1] = bf;
            }
        }
    }
    __syncthreads();

    bf16x8 b2[4][4];
    const bf16x8* B2f = (const bf16x8*)B2;
#pragma unroll
    for (int kc = 0; kc < 4; kc++)
#pragma unroll
        for (int c = 0; c < 4; c++)
            b2[kc][c] = B2f[((w * 4 + kc) * 4 + c) * 64 + l];

    f32x4 acc2[4][2];
#pragma unroll
    for (int c = 0; c < 4; c++) { acc2[c][0] = (f32x4){0.f,0.f,0.f,0.f}; acc2[c][1] = (f32x4){0.f,0.f,0.f,0.f}; }
#pragma unroll
    for (int kc = 0; kc < 4; kc++) {
        bf16x8 a0 = *(const bf16x8*)(hls + m * 136 + kc * 32 + q * 8);
        bf16x8 a1 = *(const bf16x8*)(hls + (m + 16) * 136 + kc * 32 + q * 8);
#pragma unroll
        for (int c = 0; c < 4; c++) {
            acc2[c][0] = __builtin_amdgcn_mfma_f32_16x16x32_bf16(a0, b2[kc][c], acc2[c][0], 0, 0, 0);
            acc2[c][1] = __builtin_amdgcn_mfma_f32_16x16x32_bf16(a1, b2[kc][c], acc2[c][1], 0, 0, 0);
        }
    }
#pragma unroll
    for (int c = 0; c < 4; c++) {
        int n = (w * 4 + c) * 16 + m;
        float bv = bias2 ? bias2[n] : 0.f;
        int pj = perm256(n);
#pragma unroll
        for (int hh = 0; hh < 2; hh++) {
#pragma unroll
            for (int r = 0; r < 4; r++) {
                int row = r0 + hh * 16 + q * 4 + r;
                if (row < M) {
                    float val = acc2[c][hh][r] + bv;
                    if (OMODE2 == 1) ((unsigned short*)out2)[(size_t)row * 256 + pj] = f2bf(val);
                    else             ((unsigned char*)out2)[(size_t)row * 256 + pj] = f2fp8(val);
                }
            }
        }
    }
}

// ---------------- binA body (device): bucket edges into staging ----------------
__device__ __forceinline__ void binA_body(
    char* smem, int cb,
    const int* __restrict__ idx0, const int* __restrict__ idx1,
    const int* __restrict__ boff, int* __restrict__ bfill,
    int* __restrict__ staging, int E, int NB)
{
    const int t = threadIdx.x;
    int* svals = (int*)smem;                          // 4096 ints
    unsigned char* sbk = (unsigned char*)(smem + 16384);  // 4096 bytes
    int* lhist = (int*)(smem + 20480);                // 256 ints
    int* lbase = (int*)(smem + 21504);                // 256 ints
    const int e0 = cb * BIN_CHUNK;
    const int cnt = min(E - e0, BIN_CHUNK);
    for (int b = t; b < NB; b += 256) lhist[b] = 0;
    __syncthreads();
    for (int i = t; i < cnt; i += 256) {
        int n = idx0[e0 + i];
        int m = idx1[e0 + i];
        int bk = n >> BIN_SH;
        sbk[i] = (unsigned char)bk;
        svals[i] = (m << BIN_SH) | (n & ((1 << BIN_SH) - 1));
        atomicAdd(&lhist[bk], 1);
    }
    __syncthreads();
    for (int b = t; b < NB; b += 256) {
        int h = lhist[b];
        int base = h ? atomicAdd(&bfill[b], h) : 0;
        lbase[b] = boff[b] + base;
        lhist[b] = 0;
    }
    __syncthreads();
    for (int i = t; i < cnt; i += 256) {
        int bk = sbk[i];
        int r = atomicAdd(&lhist[bk], 1);
        staging[lbase[bk] + r] = svals[i];
    }
}

// ---------------- k_main: GEMM1 + GEMM2 + binA (block ranges) ----------------
__global__ __launch_bounds__(256) void k_main(
    const float* __restrict__ x, const unsigned short* __restrict__ embB, const float* __restrict__ embed_b,
    const unsigned short* __restrict__ waB, const float* __restrict__ lin_b,
    unsigned short* __restrict__ h16, uint2* __restrict__ A16, int N, const int* __restrict__ pos_of,
    const float* __restrict__ hedge, const unsigned short* __restrict__ bembB, const float* __restrict__ bembed_b,
    const unsigned short* __restrict__ wcB, unsigned* __restrict__ Cp8, int NHE,
    const int* __restrict__ idx0, const int* __restrict__ idx1,
    const int* __restrict__ boff, int* __restrict__ bfill, int* __restrict__ staging,
    int E, int NB, int mtN, int mtNHE)
{
    __shared__ __align__(16) char smem[22528];
    const int bid = blockIdx.x;
    if (bid < mtN) {
        gemm_body<92, 3, 1>(smem, bid, x, embB, embed_b, waB, lin_b, h16, (void*)A16, N, pos_of);
    } else if (bid < mtN + mtNHE) {
        gemm_body<40, 2, 2>(smem, bid - mtN, hedge, bembB, bembed_b, wcB, nullptr, nullptr, (void*)Cp8, NHE, nullptr);
    } else {
        binA_body(smem, bid - mtN - mtNHE, idx0, idx1, boff, bfill, staging, E, NB);
    }
}

// ---------------- binB: two-pass bucket -> {rowptr, CSR} + slot table ----------------
__global__ __launch_bounds__(256) void k_binB(
    const int* __restrict__ boff, const int* __restrict__ staging,
    int* __restrict__ rowptr, int* __restrict__ sidx1, int* __restrict__ slots,
    int E, int N, int per_slot)
{
    __shared__ int lcnt[256];
    __shared__ int noofs[256];
    __shared__ int s[256];
    const int t = threadIdx.x;
    const int b = blockIdx.x;
    const int n0 = b << BIN_SH;
    const int nn = min(N - n0, 256);
    const int s0 = boff[b], s1 = boff[b + 1];
    lcnt[t] = 0;
    __syncthreads();
    for (int i = s0 + t; i < s1; i += 256)
        atomicAdd(&lcnt[staging[i] & 255], 1);
    __syncthreads();
    int v = lcnt[t];
    s[t] = v;
    __syncthreads();
#pragma unroll
    for (int ofs = 1; ofs < 256; ofs <<= 1) {
        int u = (t >= ofs) ? s[t - ofs] : 0;
        __syncthreads();
        s[t] += u;
        __syncthreads();
    }
    noofs[t] = s[t] - v;                             // exclusive in-bucket node prefix
    if (t < nn) rowptr[n0 + t] = s0 + s[t] - v;
    lcnt[t] = 0;
    if (b == 0 && t == 0) rowptr[N] = E;
    __syncthreads();
    // slot table: slots s with s*per_slot in [s0, s1)
    if (s1 > s0) {
        int sfirst = (s0 + per_slot - 1) / per_slot;
        int slast  = (s1 - 1) / per_slot;
        for (int si = sfirst + t; si <= slast; si += 256) {
            int tgt = si * per_slot - s0;
            int lo = 0, hi = nn;
            while (lo + 1 < hi) {
                int mid = (lo + hi) >> 1;
                if (noofs[mid] <= tgt) lo = mid; else hi = mid;
            }
            slots[si] = n0 + lo;
        }
    }
    for (int i = s0 + t; i < s1; i += 256) {
        int vv = staging[i];
        int nl = vv & 255;
        int r = atomicAdd(&lcnt[nl], 1);
        sidx1[s0 + noofs[nl] + r] = vv & 0xffffff00; // == idx1 << 8 (byte offset)
    }
}

// ---------------- BN1 edge stats: FULL z moments (R17 flush algebra) ----------------
__global__ __launch_bounds__(256) void k_stats(const uint2* __restrict__ A16, const unsigned char* __restrict__ Cp8b,
                                               const int* __restrict__ rowptr, const int* __restrict__ sidx1,
                                               const int* __restrict__ slots,
                                               float* __restrict__ gsum, float* __restrict__ gsq,
                                               int E, int N, int per_slot) {
    __shared__ float4 lsm4[256], lsq4[256];
    const int t = threadIdx.x;
    const int l = t & 63;
    const int wid = __builtin_amdgcn_readfirstlane(t >> 6);
    const int slot = blockIdx.x * 4 + wid;
    const unsigned lo4 = (unsigned)(l << 2);
    const long base = (long)slot * per_slot;
    const int e0 = (int)min((long)E, base);
    const int e1 = (int)min((long)E, base + per_slot);
    f32x2 smF = {0.f,0.f}, smC = {0.f,0.f};
    f32x2 sqF = {0.f,0.f}, sqC = {0.f,0.f};
    f32x2 csrF = {0.f,0.f}, csrC = {0.f,0.f};
    f32x2 aF = {0.f,0.f}, aC = {0.f,0.f};          // a of current node
    int cur_n = 0, bound = 0, runk = 0;

    auto flush = [&]() {
        if (runk) {
            float fk = (float)runk;
            f32x2 fk2 = {fk, fk};
            smF += csrF; smC += csrC;
            smF = pk_fma2(fk2, aF, smF);
            smC = pk_fma2(fk2, aC, smC);
            f32x2 tF = pk_fma2(fk2, aF, csrF + csrF);   // k*a + 2*sum_c
            f32x2 tC = pk_fma2(fk2, aC, csrC + csrC);
            sqF = pk_fma2(aF, tF, sqF);
            sqC = pk_fma2(aC, tC, sqC);
        }
        csrF = (f32x2){0.f,0.f}; csrC = (f32x2){0.f,0.f};
        runk = 0;
    };
    auto loadA = [&](int n) {
        uint2 a8 = A16[(size_t)n * 64 + l];
        aF = (f32x2){bflo(a8.x), bfhi(a8.x)};
        aC = (f32x2){bflo(a8.y), bfhi(a8.y)};
    };

    if (e0 < e1) {
        cur_n = __builtin_amdgcn_readfirstlane(slots[slot]);
        bound = __builtin_amdgcn_readfirstlane(rowptr[cur_n + 1]);
        loadA(cur_n);
    }

    auto proc = [&](int e, unsigned p) {
        if (e >= bound) {                            // scalar branch (e, bound in SGPR)
            flush();
            do { cur_n++; bound = __builtin_amdgcn_readfirstlane(rowptr[cur_n + 1]); } while (bound <= e);
            loadA(cur_n);
        }
        f32x2 vf, vc;
        fp8pair(p, vf, vc);
        csrF += vf; csrC += vc;
        sqF = pk_fma2(vf, vf, sqF);
        sqC = pk_fma2(vc, vc, sqC);
        runk++;
    };

    const int nfull = (e1 - e0) & ~7;                // e0 is 8-aligned (per_slot % 8 == 0)
    if (nfull > 0) {
        int eg = e0;
        unsigned cur[8];
        {
            int4 m0 = *(const int4*)(sidx1 + eg);
            int4 m1 = *(const int4*)(sidx1 + eg + 4);
            cur[0] = *(const unsigned*)(Cp8b + ((unsigned)m0.x + lo4));
            cur[1] = *(const unsigned*)(Cp8b + ((unsigned)m0.y + lo4));
            cur[2] = *(const unsigned*)(Cp8b + ((unsigned)m0.z + lo4));
            cur[3] = *(const unsigned*)(Cp8b + ((unsigned)m0.w + lo4));
            cur[4] = *(const unsigned*)(Cp8b + ((unsigned)m1.x + lo4));
            cur[5] = *(const unsigned*)(Cp8b + ((unsigned)m1.y + lo4));
            cur[6] = *(const unsigned*)(Cp8b + ((unsigned)m1.z + lo4));
            cur[7] = *(const unsigned*)(Cp8b + ((unsigned)m1.w + lo4));
        }
        for (;;) {
            const int en = eg + 8;
            const bool more = en < e0 + nfull;
            unsigned nxt[8];
            if (more) {
                int4 t0 = *(const int4*)(sidx1 + en);
                int4 t1 = *(const int4*)(sidx1 + en + 4);
                nxt[0] = *(const unsigned*)(Cp8b + ((unsigned)t0.x + lo4));
                nxt[1] = *(const unsigned*)(Cp8b + ((unsigned)t0.y + lo4));
                nxt[2] = *(const unsigned*)(Cp8b + ((unsigned)t0.z + lo4));
                nxt[3] = *(const unsigned*)(Cp8b + ((unsigned)t0.w + lo4));
                nxt[4] = *(const unsigned*)(Cp8b + ((unsigned)t1.x + lo4));
                nxt[5] = *(const unsigned*)(Cp8b + ((unsigned)t1.y + lo4));
                nxt[6] = *(const unsigned*)(Cp8b + ((unsigned)t1.z + lo4));
                nxt[7] = *(const unsigned*)(Cp8b + ((unsigned)t1.w + lo4));
            }
            proc(eg, cur[0]);     proc(eg + 1, cur[1]);
            proc(eg + 2, cur[2]); proc(eg + 3, cur[3]);
            proc(eg + 4, cur[4]); proc(eg + 5, cur[5]);
            proc(eg + 6, cur[6]); proc(eg + 7, cur[7]);
            if (!more) break;
#pragma unroll
            for (int i = 0; i < 8; i++) cur[i] = nxt[i];
            eg = en;
        }
    }
    for (int e = e0 + nfull; e < e1; e++)
        proc(e, *(const unsigned*)(Cp8b + ((unsigned)sidx1[e] + lo4)));
    flush();

    lsm4[t] = (float4){smF.x, smF.y, smC.x, smC.y};
    lsq4[t] = (float4){sqF.x, sqF.y, sqC.x, sqC.y};
    __syncthreads();
    const float* fm = (const float*)lsm4;
    const float* fq = (const float*)lsq4;
    float vs = fm[t] + fm[256 + t] + fm[512 + t] + fm[768 + t];
    float vq = fq[t] + fq[256 + t] + fq[512 + t] + fq[768 + t];
    atomicAdd(&gsum[t], vs);
    atomicAdd(&gsq[t], vq);
}

// ---------------- fused BN1-finalize + msg + segment softmax ----------------
__global__ __launch_bounds__(256) void k_aggr(const uint2* __restrict__ A16, const unsigned char* __restrict__ Cp8b,
                                              const int* __restrict__ rowptr, const int* __restrict__ sidx1,
                                              const int* __restrict__ pos_of,
                                              const float* __restrict__ bn1_sum, const float* __restrict__ bn1_sq,
                                              const float* __restrict__ g1, const float* __restrict__ b1,
                                              const float* __restrict__ tptr, unsigned* __restrict__ out,
                                              float invE, int N) {
    const int t = threadIdx.x;
    const int l = t & 63;
    const int wid = __builtin_amdgcn_readfirstlane(t >> 6);
    const int n = blockIdx.x * 4 + wid;
    if (n >= N) return;

    const int e0 = __builtin_amdgcn_readfirstlane(rowptr[n]);
    const int e1 = __builtin_amdgcn_readfirstlane(rowptr[n + 1]);
    const int pn = __builtin_amdgcn_readfirstlane(pos_of[n]);

    const float tt = tptr[0];
    const float4 sum4 = ((const float4*)bn1_sum)[l];
    const float4 sq4  = ((const float4*)bn1_sq)[l];
    const float2 gf = ((const float2*)g1)[l];
    const float2 gc = ((const float2*)(g1 + 128))[l];
    const float2 bf2 = ((const float2*)b1)[l];
    const float2 bc2 = ((const float2*)(b1 + 128))[l];
    auto mkss = [&](float sum, float sq, float gg, float bb, float& sc, float& sh) {
        float mu = sum * invE;
        float var = sq * invE - mu * mu;
        sc = gg * rsqrtf(var + EPS_BN);
        sh = fmaf(-mu, sc, bb);
    };
    float scx, shx, scy, shy, scz, shz, scw, shw;
    mkss(sum4.x, sq4.x, gf.x, bf2.x, scx, shx);
    mkss(sum4.y, sq4.y, gf.y, bf2.y, scy, shy);
    mkss(sum4.z, sq4.z, gc.x, bc2.x, scz, shz);
    mkss(sum4.w, sq4.w, gc.y, bc2.y, scw, shw);
    const f32x2 sF  = {-scx * LOG2E, -scy * LOG2E};
    const f32x2 sC  = { scz * LOG2E,  scw * LOG2E};

    uint2 a8 = A16[(size_t)n * 64 + l];
    f32x2 aF = {bflo(a8.x), bfhi(a8.x)}, aC = {bflo(a8.y), bfhi(a8.y)};
    const f32x2 bF = pk_fma2(aF, sF, (f32x2){-shx * LOG2E, -shy * LOG2E});
    const f32x2 bC = pk_fma2(aC, sC, (f32x2){ shz * LOG2E,  shw * LOG2E});

    if (e0 >= e1) { out[(size_t)pn * 64 + l] = 0u; return; }

    const unsigned lo4 = (unsigned)(l << 2);
    f32x2 den = {0.f,0.f}, num = {0.f,0.f};

    auto G = [&](int e) -> unsigned {
        return *(const unsigned*)(Cp8b + ((unsigned)sidx1[e] + lo4));
    };
    auto procg = [&](unsigned p) {
        f32x2 vf, vc;
        fp8pair(p, vf, vc);
        f32x2 argf = pk_fma2(vf, sF, bF);            // -zf_hat * log2e
        f32x2 argc = pk_fma2(vc, sC, bC);            //  zc_hat * log2e
        f32x2 ef = {fexp2(argf.x), fexp2(argf.y)};
        f32x2 uu = {fexp2(argc.x), fexp2(argc.y)};
        f32x2 d1 = ef + 1.f;
        f32x2 u1 = uu + 1.f;
        f32x2 sig = {__builtin_amdgcn_rcpf(d1.x), __builtin_amdgcn_rcpf(d1.y)};
        f32x2 lg = {flog2(u1.x), flog2(u1.y)};
        f32x2 M = sig * lg;
        f32x2 tM = M * tt;
        f32x2 w = {fexp2(tM.x), fexp2(tM.y)};
        den += w;
        num = pk_fma2(M, w, num);
    };

    const int cnt = e1 - e0;                         // scalar
    unsigned cur[8];
#pragma unroll
    for (int i = 0; i < 8; i++)
        if (i < cnt) cur[i] = G(e0 + i);             // scalar-guarded loads

    int e = e0;
    while (e + 8 < e1) {                             // full group of 8 present
        unsigned nxt[8];
#pragma unroll
        for (int i = 0; i < 8; i++)
            if (e + 8 + i < e1) nxt[i] = G(e + 8 + i);   // scalar-guarded prefetch
#pragma unroll
        for (int i = 0; i < 8; i++) procg(cur[i]);
#pragma unroll
        for (int i = 0; i < 8; i++) cur[i] = nxt[i];
        e += 8;
    }
    const int rem = e1 - e;                          // 1..8, scalar
#pragma unroll
    for (int i = 0; i < 8; i++)
        if (i < rem) procg(cur[i]);                  // scalar-branch tail

    float ox = LN2 * num.x * __builtin_amdgcn_rcpf(den.x);
    float oy = LN2 * num.y * __builtin_amdgcn_rcpf(den.y);
    out[(size_t)pn * 64 + l] = pack2bf(ox, oy);
}

// ---------------- k_tail (cooperative): bn2stats -> h2pool -> head ----------------
__global__ __launch_bounds__(256) void k_tail(
    const unsigned* __restrict__ outw, const unsigned short* __restrict__ h16,
    const int* __restrict__ gptr,
    float* __restrict__ bn2_sum, float* __restrict__ bn2_sq,
    const float* __restrict__ g2, const float* __restrict__ b2,
    float* __restrict__ pooled, const int* __restrict__ gcount,
    const float* __restrict__ l1w, const float* __restrict__ l1b,
    const float* __restrict__ outw_h, const float* __restrict__ outb,
    float* __restrict__ dout, int N, float invN)
{
    cg::grid_group grid = cg::this_grid();
    const int t = threadIdx.x;
    const int bid = blockIdx.x;

    // ---- phase A: BN2 stats (packed-word loads + LDS reduce) ----
    {
        __shared__ float4 ls[256];
        const int w = t & 63;
        const int rg = t >> 6;
        f32x2 sm = {0.f,0.f}, s2 = {0.f,0.f};
        for (int n = bid * 4 + rg; n < N; n += gridDim.x * 4) {
            unsigned v = outw[(size_t)n * 64 + w];
            f32x2 x = {bflo(v), bfhi(v)};
            sm += x;
            s2 = pk_fma2(x, x, s2);
        }
        ls[t] = (float4){sm.x, sm.y, s2.x, s2.y};
        __syncthreads();
        if (t < 64) {
            float4 a = ls[t], b = ls[t + 64], c = ls[t + 128], d = ls[t + 192];
            float vx = a.x + b.x + c.x + d.x;
            float vy = a.y + b.y + c.y + d.y;
            float vz = a.z + b.z + c.z + d.z;
            float vw = a.w + b.w + c.w + d.w;
            if (vx != 0.f) atomicAdd(&bn2_sum[2 * t], vx);
            if (vy != 0.f) atomicAdd(&bn2_sum[2 * t + 1], vy);
            if (vz != 0.f) atomicAdd(&bn2_sq[2 * t], vz);
            if (vw != 0.f) atomicAdd(&bn2_sq[2 * t + 1], vw);
        }
    }
    grid.sync();

    // ---- phase B: BN2-finalize + residual+softplus + mean-pool (dense) ----
    {
        const unsigned short* out16 = (const unsigned short*)outw;
        const int g = bid & 127;
        const int sp = ((bid >> 7) << 1) + (t >> 7);     // 0..15
        const int c = t & 127;
        float mu = bn2_sum[c] * invN;
        float var = bn2_sq[c] * invN - mu * mu;
        float sc = g2[c] * rsqrtf(var + EPS_BN);
        float sh = fmaf(-mu, sc, b2[c]);
        const int i0 = gptr[g], i1 = gptr[g + 1];
        float acc = 0.f;
        for (int i = i0 + sp; i < i1; i += 16) {
            float v = fmaf(bfu16(out16[(size_t)i * 128 + c]), sc, sh) + bfu16(h16[(size_t)i * 128 + c]);
            acc += softplus_fast(v);
        }
        if (acc != 0.f) atomicAdd(&pooled[g * 128 + c], acc);
    }
    grid.sync();

    // ---- phase C: head ----
    if (bid < 128) {
        __shared__ float p[128];
        __shared__ float red[256];
        const int g = bid;
        const int j = t;
        if (j < 128) {
            float cnt = (float)max(gcount[g], 1);
            p[j] = pooled[g * 128 + j] / cnt;
        }
        __syncthreads();
        float acc = l1b[j];
        for (int k = 0; k < 128; k++) acc = fmaf(p[k], l1w[k * 256 + j], acc);
        red[j] = softplus_fast(acc) * outw_h[j];
        __syncthreads();
        for (int s = 128; s > 0; s >>= 1) {
            if (j < s) red[j] += red[j + s];
            __syncthreads();
        }
        if (j == 0) dout[g] = red[0] + outb[0];
    }
}

// ---------------- launch ----------------
extern "C" void kernel_launch(void* const* d_in, const int* in_sizes, int n_in,
                              void* d_out, int out_size, void* d_ws, size_t ws_size,
                              hipStream_t stream) {
    const float* x        = (const float*)d_in[0];
    const float* hedge    = (const float*)d_in[1];
    const int*   iri      = (const int*)d_in[2];
    const int*   batch    = (const int*)d_in[3];
    const float* embed_w  = (const float*)d_in[5];
    const float* embed_b  = (const float*)d_in[6];
    const float* bembed_w = (const float*)d_in[7];
    const float* bembed_b = (const float*)d_in[8];
    const float* lin_w    = (const float*)d_in[9];
    const float* lin_b    = (const float*)d_in[10];
    const float* bn1_g    = (const float*)d_in[11];
    const float* bn1_b    = (const float*)d_in[12];
    const float* bn2_g    = (const float*)d_in[13];
    const float* bn2_b    = (const float*)d_in[14];
    const float* aggr_t   = (const float*)d_in[15];
    const float* l1_w     = (const float*)d_in[16];
    const float* l1_b     = (const float*)d_in[17];
    const float* out_w    = (const float*)d_in[18];
    const float* out_b    = (const float*)d_in[19];

    const int N   = in_sizes[0] / 92;
    const int NHE = in_sizes[1] / 40;
    const int E   = in_sizes[2] / 3;
    const int* idx0 = iri;
    const int* idx1 = iri + E;

    float* ws = (float*)d_ws;
    size_t off = 0;
    auto alloc = [&](size_t elems) -> float* {
        float* p = ws + off;
        off += (elems + 63) & ~(size_t)63;
        return p;
    };
    unsigned short* h16 = (unsigned short*)alloc((size_t)N * 64);   // N*128 bf16 (pooling order)
    uint2* A16    = (uint2*)alloc((size_t)N * 128);                 // N*256 bf16 packed
    unsigned* Cp8 = (unsigned*)alloc((size_t)NHE * 64);             // NHE*256 fp8 packed
    unsigned short* embB  = (unsigned short*)alloc(6144);
    unsigned short* bembB = (unsigned short*)alloc(4096);
    unsigned short* waB   = (unsigned short*)alloc(16384);
    unsigned short* wcB   = (unsigned short*)alloc(16384);
    int*   rowptr = (int*)alloc((size_t)N + 1);
    int*   boff   = (int*)alloc(260);
    int*   sidx1  = (int*)alloc((size_t)E + 8);
    int*   staging = (int*)alloc((size_t)E + 8);
    int*   gptr   = (int*)alloc(129);
    int*   pos_of = (int*)alloc((size_t)N);
    int*   slots  = (int*)alloc(8200);
    unsigned* outbuf = (unsigned*)alloc((size_t)N * 64);            // N*128 bf16 (pooling order)
    // contiguous zero region (zeroed by k_front phase 0)
    float* zbase  = ws + off;
    int*   bsum   = (int*)alloc(256);
    int*   bfill  = (int*)alloc(256);
    int*   gfill  = (int*)alloc(128);
    int*   gcount = (int*)alloc(128);
    float* bn1_sum = alloc(256);
    float* bn1_sq  = alloc(256);
    float* bn2_sum = alloc(128);
    float* bn2_sq  = alloc(128);
    float* pooled  = alloc(128 * 128);
    int zwords = (int)((ws + off) - zbase);
    (void)ws_size;  // ~81MB; fit verified

    const int NB = (N + 255) >> BIN_SH;
    const int EB = (E + BIN_CHUNK - 1) / BIN_CHUNK;
    const int GB = (N + 255) / 256;

    // k_front (cooperative): zero -> prepw+counts -> scans+scatterpos
    {
        int FG = 320 + EB;                           // >= 1 + GB as well (516 vs 197)
        void* args[] = {
            (void*)&embed_w, (void*)&bembed_w, (void*)&lin_w,
            (void*)&embB, (void*)&bembB, (void*)&waB, (void*)&wcB,
            (void*)&idx0, (void*)&batch,
            (void*)&bsum, (void*)&gcount,
            (void*)&zbase, (void*)&zwords,
            (void*)&boff, (void*)&gptr, (void*)&gfill, (void*)&pos_of,
            (void*)&E, (void*)&N, (void*)&NB, (void*)&EB, (void*)&GB
        };
        hipLaunchCooperativeKernel((const void*)k_front, dim3(FG), dim3(256), args, 0, stream);
    }

    // GEMM1 + GEMM2 + binA (merged block ranges)
    const int mtN   = (N + 31) / 32;
    const int mtNHE = (NHE + 31) / 32;
    k_main<<<mtN + mtNHE + EB, 256, 0, stream>>>(
        x, embB, embed_b, waB, lin_b, h16, A16, N, pos_of,
        hedge, bembB, bembed_b, wcB, Cp8, NHE,
        idx0, idx1, boff, bfill, staging, E, NB, mtN, mtNHE);

    // binB: two-pass bucket -> {rowptr, CSR} + slot table
    const int EDGE_BLOCKS = 2048;
    const int NSLOTS = EDGE_BLOCKS * 4;
    int per_slot = ((E + NSLOTS - 1) / NSLOTS + 7) & ~7;
    k_binB<<<NB, 256, 0, stream>>>(boff, staging, rowptr, sidx1, slots, E, N, per_slot);

    // BN1 stats: full z moments in one edge pass (slot-start)
    k_stats<<<EDGE_BLOCKS, 256, 0, stream>>>(A16, (const unsigned char*)Cp8, rowptr, sidx1, slots,
                                             bn1_sum, bn1_sq, E, N, per_slot);

    // fused BN1-finalize + message + softmax aggregation (out in pooling order)
    k_aggr<<<(N + 3) / 4, 256, 0, stream>>>(A16, (const unsigned char*)Cp8, rowptr, sidx1, pos_of,
                                            bn1_sum, bn1_sq, bn1_g, bn1_b, aggr_t, outbuf,
                                            1.0f / (float)E, N);

    // k_tail (cooperative): bn2stats -> h2pool -> head
    {
        float invN = 1.0f / (float)N;
        const unsigned* outw = outbuf;
        void* args[] = {
            (void*)&outw, (void*)&h16, (void*)&gptr,
            (void*)&bn2_sum, (void*)&bn2_sq,
            (void*)&bn2_g, (void*)&bn2_b,
            (void*)&pooled, (void*)&gcount,
            (void*)&l1_w, (void*)&l1_b, (void*)&out_w, (void*)&out_b,
            (void*)&d_out, (void*)&N, (void*)&invN
        };
        hipLaunchCooperativeKernel((const void*)k_tail, dim3(1024), dim3(256), args, 0, stream);
    }
}

// Round 17
// 383.363 us; speedup vs baseline: 1.7895x; 1.7895x over previous
//
#include <hip/hip_runtime.h>
#include <hip/hip_bf16.h>

// CrystalHypergraphConv — MI355X implementation.
//
// z[e] = A[idx0[e]] + C[idx1[e]];  A [N,256] bf16-packed; C [NHE,256]
// fp8-e4m3-packed. Lane l owns channels {2l,2l+1,128+2l,129+2l}.
//
// R32 -> R33: REVERT cooperative-kernel consolidation (falsified hard:
// grid.sync() on gfx950 costs ~100us/sync at 1024 blocks — k_tail alone
// 216us vs ~25us for the 3 kernels it replaced). Restore R31 (388.6us):
//  - k_pre: prepw + counts (block ranges)
//  - k_scan: scans + scatterpos (local gptr per block, no intra-kernel dep)
//  - k_main: GEMM1 + GEMM2 + binA (block ranges)
//  - k_binB, k_stats, k_aggr, k_bn2stats, k_h2pool, k_head
//  Edge passes at the confirmed ~1.4TB/s random-gather pattern ceiling.

#define EPS_BN 1e-5f
#define LOG2E 1.4426950408889634f
#define LN2   0.6931471805599453f

#define BIN_SH 8
#define BIN_CHUNK 4096

typedef __attribute__((ext_vector_type(8))) short bf16x8;
typedef __attribute__((ext_vector_type(4))) float f32x4;
typedef __attribute__((ext_vector_type(2))) float f32x2;

__device__ __forceinline__ float fexp2(float x) {
#if __has_builtin(__builtin_amdgcn_exp2f)
    return __builtin_amdgcn_exp2f(x);
#else
    return __expf(x * LN2);
#endif
}
__device__ __forceinline__ float flog2(float x) {
#if __has_builtin(__builtin_amdgcn_logf)
    return __builtin_amdgcn_logf(x);
#else
    return __logf(x) * LOG2E;
#endif
}
__device__ __forceinline__ float softplus_fast(float x) {
    return LN2 * flog2(1.f + fexp2(x * LOG2E));
}

__device__ __forceinline__ f32x2 pk_fma2(f32x2 a, f32x2 b, f32x2 c) {
#if __has_builtin(__builtin_elementwise_fma)
    return __builtin_elementwise_fma(a, b, c);
#else
    return (f32x2){fmaf(a.x, b.x, c.x), fmaf(a.y, b.y, c.y)};
#endif
}

__device__ __forceinline__ unsigned short f2bf(float f) {
    unsigned u = __float_as_uint(f);
    unsigned r = (u + 0x7fffu + ((u >> 16) & 1u)) >> 16;   // RNE
    return (unsigned short)r;
}
__device__ __forceinline__ float bflo(unsigned u) { return __uint_as_float(u << 16); }
__device__ __forceinline__ float bfhi(unsigned u) { return __uint_as_float(u & 0xffff0000u); }
__device__ __forceinline__ float bfu16(unsigned short v) { return __uint_as_float(((unsigned)v) << 16); }
__device__ __forceinline__ unsigned pack2bf(float x, float y) {
    return (unsigned)f2bf(x) | ((unsigned)f2bf(y) << 16);
}

// ---- fp8 e4m3 encode/decode (OCP; HW path on gfx950) ----
#if __has_builtin(__builtin_amdgcn_cvt_pk_f32_fp8) && __has_builtin(__builtin_amdgcn_cvt_pk_fp8_f32)
#define HW_FP8 1
#else
#define HW_FP8 0
#endif

__device__ __forceinline__ unsigned char f2fp8(float f) {
#if HW_FP8
    int r = __builtin_amdgcn_cvt_pk_fp8_f32(f, f, 0, false);
    return (unsigned char)(r & 0xff);
#else
    unsigned u = __float_as_uint(f);
    unsigned s = (u >> 24) & 0x80u;
    float af = fabsf(f);
    if (!(af >= 0.015625f)) {
        int m = (int)rintf(af * 512.f);
        if (m > 7) m = 7;
        return (unsigned char)(s | (unsigned)m);
    }
    if (af > 448.f) return (unsigned char)(s | 0x7e);
    unsigned au = __float_as_uint(af);
    unsigned r = au + 0x7ffffu + ((au >> 20) & 1u);
    int e8 = (int)(r >> 23) - 120;
    unsigned m = (r >> 20) & 7u;
    if (e8 > 15 || (e8 == 15 && m == 7)) return (unsigned char)(s | 0x7e);
    return (unsigned char)(s | ((unsigned)e8 << 3) | m);
#endif
}

// decode packed word -> lo pair (bytes 0,1 = f channels), hi pair (bytes 2,3 = c channels)
__device__ __forceinline__ void fp8pair(unsigned p, f32x2& lo, f32x2& hi) {
#if HW_FP8
    lo = __builtin_amdgcn_cvt_pk_f32_fp8((int)p, false);
    hi = __builtin_amdgcn_cvt_pk_f32_fp8((int)p, true);
#else
    auto dec = [](unsigned byte) -> float {
        unsigned s = (byte & 0x80u) << 24;
        unsigned em = byte & 0x7fu;
        float nrm = __uint_as_float(s | ((em << 20) + 0x3C000000u));
        float sub = __uint_as_float(s | 0x3F800000u) * (float)em * 0.001953125f;
        return (em >= 8) ? nrm : sub;
    };
    lo = (f32x2){dec(p & 0xff), dec((p >> 8) & 0xff)};
    hi = (f32x2){dec((p >> 16) & 0xff), dec(p >> 24)};
#endif
}

__device__ __forceinline__ int perm256(int j) {
    return (j < 128) ? ((j >> 1) * 4 + (j & 1)) : (((j - 128) >> 1) * 4 + 2 + (j & 1));
}

// ---------------- k_pre: weight prep + idx0-bucket & batch counts ----------------
__global__ __launch_bounds__(256) void k_pre(const float* __restrict__ ew, const float* __restrict__ bw,
                                             const float* __restrict__ lw,
                                             unsigned short* __restrict__ embB, unsigned short* __restrict__ bembB,
                                             unsigned short* __restrict__ waB, unsigned short* __restrict__ wcB,
                                             const int* __restrict__ idx0, const int* __restrict__ batch,
                                             int* __restrict__ bsum, int* __restrict__ gcount,
                                             int E, int N, int NB) {
    const int t = threadIdx.x;
    const int bid = blockIdx.x;
    if (bid >= 320) {                                // ---- counts ----
        __shared__ int lhist[256];
        __shared__ int lbat[128];
        const int cb = bid - 320;
        lhist[t] = 0;
        if (t < 128) lbat[t] = 0;
        __syncthreads();
        const int e0 = cb * BIN_CHUNK;
        const int ecnt = min(E - e0, BIN_CHUNK);
        for (int i = t; i < ecnt; i += 256)
            atomicAdd(&lhist[idx0[e0 + i] >> BIN_SH], 1);
        const int n0 = cb * BIN_CHUNK;
        const int ncnt = min(N - n0, BIN_CHUNK);
        for (int i = t; i < ncnt; i += 256)
            atomicAdd(&lbat[batch[n0 + i]], 1);
        __syncthreads();
        if (t < NB && lhist[t]) atomicAdd(&bsum[t], lhist[t]);
        if (t < 128 && lbat[t]) atomicAdd(&gcount[t], lbat[t]);
        return;
    }
    int i = bid * 256 + t;                           // ---- prepw (0..81919) ----
    if (i >= 81920) return;
    unsigned short* dst;
    int f, NKC, CT, mode;
    if (i < 12288)      { dst = embB;  f = i;         NKC = 3; CT = 2; mode = 0; }
    else if (i < 20480) { dst = bembB; f = i - 12288; NKC = 2; CT = 2; mode = 1; }
    else if (i < 53248) { dst = waB;   f = i - 20480; NKC = 4; CT = 4; mode = 2; }
    else                { dst = wcB;   f = i - 53248; NKC = 4; CT = 4; mode = 3; }
    int j = f & 7, l = (f >> 3) & 63;
    int r2 = f >> 9;
    int c = r2 % CT;
    int r3 = r2 / CT;
    int kc = r3 % NKC, w = r3 / NKC;
    int k = kc * 32 + ((l >> 4) & 3) * 8 + j;
    int n = (w * CT + c) * 16 + (l & 15);
    float v;
    if (mode == 0)      v = (k < 92) ? ew[k * 128 + n] : 0.f;
    else if (mode == 1) v = (k < 40) ? bw[k * 128 + n] : 0.f;
    else if (mode == 2) v = lw[k * 256 + n] + lw[(k + 256) * 256 + n];
    else                v = lw[(k + 128) * 256 + n];
    dst[f] = f2bf(v);
}

// ---------------- k_scan: block 0 = boff/gptr scans; blocks >=1 = scatterpos ----------------
// scatterpos blocks compute gptr LOCALLY from gcount (no dependency on block 0).
__global__ __launch_bounds__(256) void k_scan(const int* __restrict__ bsum, int* __restrict__ boff,
                                              const int* __restrict__ gcount, int* __restrict__ gptr,
                                              const int* __restrict__ batch, int* __restrict__ gfill,
                                              int* __restrict__ pos_of, int N, int NB) {
    __shared__ int s[256];
    const int t = threadIdx.x;
    const int bid = blockIdx.x;
    if (bid == 0) {                                  // ---- scans ----
        int v = (t < NB) ? bsum[t] : 0;
        s[t] = v;
        __syncthreads();
#pragma unroll
        for (int ofs = 1; ofs < 256; ofs <<= 1) {
            int u = (t >= ofs) ? s[t - ofs] : 0;
            __syncthreads();
            s[t] += u;
            __syncthreads();
        }
        if (t < NB) boff[t] = s[t] - v;              // exclusive bucket offsets
        if (t == NB - 1) boff[NB] = s[t];            // total = E
        __syncthreads();
        int gv = (t < 128) ? gcount[t] : 0;
        s[t] = gv;
        __syncthreads();
#pragma unroll
        for (int ofs = 1; ofs < 128; ofs <<= 1) {
            int u = (t >= ofs && t < 128) ? s[t - ofs] : 0;
            __syncthreads();
            if (t < 128) s[t] += u;
            __syncthreads();
        }
        if (t < 128) gptr[t + 1] = s[t];
        if (t == 0) gptr[0] = 0;
        return;
    }
    // ---- scatterpos with local gptr ----
    __shared__ int lg[128];
    int gv = (t < 128) ? gcount[t] : 0;
    s[t] = gv;
    __syncthreads();
#pragma unroll
    for (int ofs = 1; ofs < 128; ofs <<= 1) {
        int u = (t >= ofs && t < 128) ? s[t - ofs] : 0;
        __syncthreads();
        if (t < 128) s[t] += u;
        __syncthreads();
    }
    if (t < 128) lg[t] = s[t] - gv;                  // exclusive gptr
    __syncthreads();
    int i = (bid - 1) * 256 + t;
    if (i < N) {
        int g = batch[i];
        pos_of[i] = lg[g] + atomicAdd(&gfill[g], 1);
    }
}

// ---------------- GEMM body (device) ----------------
// OMODE2: 1 = bf16-packed A + bf16 h out (h at pos_of[row]); 2 = fp8-packed C out
template<int KIN, int NKC1, int OMODE2>
__device__ __forceinline__ void gemm_body(
    char* smem, int blk,
    const float* __restrict__ in, const unsigned short* __restrict__ B1, const float* __restrict__ bias1,
    const unsigned short* __restrict__ B2, const float* __restrict__ bias2,
    unsigned short* __restrict__ hout, void* __restrict__ out2, int M,
    const int* __restrict__ pos_of)
{
    const int r0 = blk * 32;
    const int t = threadIdx.x;
    const int w = t >> 6;
    const int l = t & 63;
    const int m = l & 15, q = l >> 4;

    unsigned short* als = (unsigned short*)smem;                  // 32*NKC1*32 shorts
    unsigned short* hls = als + 32 * NKC1 * 32;                   // 32*136 shorts

    const int KP = NKC1 * 32;
    for (int i = t; i < 32 * KP; i += 256) {
        int r = i / KP, k = i - r * KP;
        int gr = r0 + r;
        float v = (gr < M && k < KIN) ? in[(size_t)gr * KIN + k] : 0.f;
        int idx = (((r >> 4) * NKC1 + (k >> 5)) * 64 + ((k >> 3) & 3) * 16 + (r & 15)) * 8 + (k & 7);
        als[idx] = f2bf(v);
    }
    bf16x8 b1[NKC1][2];
    const bf16x8* B1f = (const bf16x8*)B1;
#pragma unroll
    for (int kc = 0; kc < NKC1; kc++)
#pragma unroll
        for (int c = 0; c < 2; c++)
            b1[kc][c] = B1f[((w * NKC1 + kc) * 2 + c) * 64 + l];
    __syncthreads();

    f32x4 acc1[2][2];
#pragma unroll
    for (int c = 0; c < 2; c++) { acc1[c][0] = (f32x4){0.f,0.f,0.f,0.f}; acc1[c][1] = (f32x4){0.f,0.f,0.f,0.f}; }
    const bf16x8* af = (const bf16x8*)als;
#pragma unroll
    for (int kc = 0; kc < NKC1; kc++) {
        bf16x8 a0 = af[kc * 64 + l];
        bf16x8 a1 = af[(NKC1 + kc) * 64 + l];
#pragma unroll
        for (int c = 0; c < 2; c++) {
            acc1[c][0] = __builtin_amdgcn_mfma_f32_16x16x32_bf16(a0, b1[kc][c], acc1[c][0], 0, 0, 0);
            acc1[c][1] = __builtin_amdgcn_mfma_f32_16x16x32_bf16(a1, b1[kc][c], acc1[c][1], 0, 0, 0);
        }
    }
#pragma unroll
    for (int c = 0; c < 2; c++) {
        int n1 = (w * 2 + c) * 16 + m;
        float bv = bias1[n1];
#pragma unroll
        for (int hh = 0; hh < 2; hh++) {
#pragma unroll
            for (int r = 0; r < 4; r++) {
                int row = hh * 16 + q * 4 + r;
                float val = acc1[c][hh][r] + bv;
                unsigned short bf = f2bf(val);
                hls[row * 136 + n1] = bf;
                if (OMODE2 == 1 && r0 + row < M)
                    hout[(size_t)pos_of[r0 + row] * 128 + n1] = bf;
            }
        }
    }
    __syncthreads();

    bf16x8 b2[4][4];
    const bf16x8* B2f = (const bf16x8*)B2;
#pragma unroll
    for (int kc = 0; kc < 4; kc++)
#pragma unroll
        for (int c = 0; c < 4; c++)
            b2[kc][c] = B2f[((w * 4 + kc) * 4 + c) * 64 + l];

    f32x4 acc2[4][2];
#pragma unroll
    for (int c = 0; c < 4; c++) { acc2[c][0] = (f32x4){0.f,0.f,0.f,0.f}; acc2[c][1] = (f32x4){0.f,0.f,0.f,0.f}; }
#pragma unroll
    for (int kc = 0; kc < 4; kc++) {
        bf16x8 a0 = *(const bf16x8*)(hls + m * 136 + kc * 32 + q * 8);
        bf16x8 a1 = *(const bf16x8*)(hls + (m + 16) * 136 + kc * 32 + q * 8);
#pragma unroll
        for (int c = 0; c < 4; c++) {
            acc2[c][0] = __builtin_amdgcn_mfma_f32_16x16x32_bf16(a0, b2[kc][c], acc2[c][0], 0, 0, 0);
            acc2[c][1] = __builtin_amdgcn_mfma_f32_16x16x32_bf16(a1, b2[kc][c], acc2[c][1], 0, 0, 0);
        }
    }
#pragma unroll
    for (int c = 0; c < 4; c++) {
        int n = (w * 4 + c) * 16 + m;
        float bv = bias2 ? bias2[n] : 0.f;
        int pj = perm256(n);
#pragma unroll
        for (int hh = 0; hh < 2; hh++) {
#pragma unroll
            for (int r = 0; r < 4; r++) {
                int row = r0 + hh * 16 + q * 4 + r;
                if (row < M) {
                    float val = acc2[c][hh][r] + bv;
                    if (OMODE2 == 1) ((unsigned short*)out2)[(size_t)row * 256 + pj] = f2bf(val);
                    else             ((unsigned char*)out2)[(size_t)row * 256 + pj] = f2fp8(val);
                }
            }
        }
    }
}

// ---------------- binA body (device): bucket edges into staging ----------------
__device__ __forceinline__ void binA_body(
    char* smem, int cb,
    const int* __restrict__ idx0, const int* __restrict__ idx1,
    const int* __restrict__ boff, int* __restrict__ bfill,
    int* __restrict__ staging, int E, int NB)
{
    const int t = threadIdx.x;
    int* svals = (int*)smem;                          // 4096 ints
    unsigned char* sbk = (unsigned char*)(smem + 16384);  // 4096 bytes
    int* lhist = (int*)(smem + 20480);                // 256 ints
    int* lbase = (int*)(smem + 21504);                // 256 ints
    const int e0 = cb * BIN_CHUNK;
    const int cnt = min(E - e0, BIN_CHUNK);
    for (int b = t; b < NB; b += 256) lhist[b] = 0;
    __syncthreads();
    for (int i = t; i < cnt; i += 256) {
        int n = idx0[e0 + i];
        int m = idx1[e0 + i];
        int bk = n >> BIN_SH;
        sbk[i] = (unsigned char)bk;
        svals[i] = (m << BIN_SH) | (n & ((1 << BIN_SH) - 1));
        atomicAdd(&lhist[bk], 1);
    }
    __syncthreads();
    for (int b = t; b < NB; b += 256) {
        int h = lhist[b];
        int base = h ? atomicAdd(&bfill[b], h) : 0;
        lbase[b] = boff[b] + base;
        lhist[b] = 0;
    }
    __syncthreads();
    for (int i = t; i < cnt; i += 256) {
        int bk = sbk[i];
        int r = atomicAdd(&lhist[bk], 1);
        staging[lbase[bk] + r] = svals[i];
    }
}

// ---------------- k_main: GEMM1 + GEMM2 + binA (block ranges) ----------------
__global__ __launch_bounds__(256) void k_main(
    const float* __restrict__ x, const unsigned short* __restrict__ embB, const float* __restrict__ embed_b,
    const unsigned short* __restrict__ waB, const float* __restrict__ lin_b,
    unsigned short* __restrict__ h16, uint2* __restrict__ A16, int N, const int* __restrict__ pos_of,
    const float* __restrict__ hedge, const unsigned short* __restrict__ bembB, const float* __restrict__ bembed_b,
    const unsigned short* __restrict__ wcB, unsigned* __restrict__ Cp8, int NHE,
    const int* __restrict__ idx0, const int* __restrict__ idx1,
    const int* __restrict__ boff, int* __restrict__ bfill, int* __restrict__ staging,
    int E, int NB, int mtN, int mtNHE)
{
    __shared__ __align__(16) char smem[22528];
    const int bid = blockIdx.x;
    if (bid < mtN) {
        gemm_body<92, 3, 1>(smem, bid, x, embB, embed_b, waB, lin_b, h16, (void*)A16, N, pos_of);
    } else if (bid < mtN + mtNHE) {
        gemm_body<40, 2, 2>(smem, bid - mtN, hedge, bembB, bembed_b, wcB, nullptr, nullptr, (void*)Cp8, NHE, nullptr);
    } else {
        binA_body(smem, bid - mtN - mtNHE, idx0, idx1, boff, bfill, staging, E, NB);
    }
}

// ---------------- binB: two-pass bucket -> {rowptr, CSR} + slot table ----------------
__global__ __launch_bounds__(256) void k_binB(
    const int* __restrict__ boff, const int* __restrict__ staging,
    int* __restrict__ rowptr, int* __restrict__ sidx1, int* __restrict__ slots,
    int E, int N, int per_slot)
{
    __shared__ int lcnt[256];
    __shared__ int noofs[256];
    __shared__ int s[256];
    const int t = threadIdx.x;
    const int b = blockIdx.x;
    const int n0 = b << BIN_SH;
    const int nn = min(N - n0, 256);
    const int s0 = boff[b], s1 = boff[b + 1];
    lcnt[t] = 0;
    __syncthreads();
    for (int i = s0 + t; i < s1; i += 256)
        atomicAdd(&lcnt[staging[i] & 255], 1);
    __syncthreads();
    int v = lcnt[t];
    s[t] = v;
    __syncthreads();
#pragma unroll
    for (int ofs = 1; ofs < 256; ofs <<= 1) {
        int u = (t >= ofs) ? s[t - ofs] : 0;
        __syncthreads();
        s[t] += u;
        __syncthreads();
    }
    noofs[t] = s[t] - v;                             // exclusive in-bucket node prefix
    if (t < nn) rowptr[n0 + t] = s0 + s[t] - v;
    lcnt[t] = 0;
    if (b == 0 && t == 0) rowptr[N] = E;
    __syncthreads();
    // slot table: slots s with s*per_slot in [s0, s1)
    if (s1 > s0) {
        int sfirst = (s0 + per_slot - 1) / per_slot;
        int slast  = (s1 - 1) / per_slot;
        for (int si = sfirst + t; si <= slast; si += 256) {
            int tgt = si * per_slot - s0;
            int lo = 0, hi = nn;
            while (lo + 1 < hi) {
                int mid = (lo + hi) >> 1;
                if (noofs[mid] <= tgt) lo = mid; else hi = mid;
            }
            slots[si] = n0 + lo;
        }
    }
    for (int i = s0 + t; i < s1; i += 256) {
        int vv = staging[i];
        int nl = vv & 255;
        int r = atomicAdd(&lcnt[nl], 1);
        sidx1[s0 + noofs[nl] + r] = vv & 0xffffff00; // == idx1 << 8 (byte offset)
    }
}

// ---------------- BN1 edge stats: FULL z moments (R17 flush algebra) ----------------
__global__ __launch_bounds__(256) void k_stats(const uint2* __restrict__ A16, const unsigned char* __restrict__ Cp8b,
                                               const int* __restrict__ rowptr, const int* __restrict__ sidx1,
                                               const int* __restrict__ slots,
                                               float* __restrict__ gsum, float* __restrict__ gsq,
                                               int E, int N, int per_slot) {
    __shared__ float4 lsm4[256], lsq4[256];
    const int t = threadIdx.x;
    const int l = t & 63;
    const int wid = __builtin_amdgcn_readfirstlane(t >> 6);
    const int slot = blockIdx.x * 4 + wid;
    const unsigned lo4 = (unsigned)(l << 2);
    const long base = (long)slot * per_slot;
    const int e0 = (int)min((long)E, base);
    const int e1 = (int)min((long)E, base + per_slot);
    f32x2 smF = {0.f,0.f}, smC = {0.f,0.f};
    f32x2 sqF = {0.f,0.f}, sqC = {0.f,0.f};
    f32x2 csrF = {0.f,0.f}, csrC = {0.f,0.f};
    f32x2 aF = {0.f,0.f}, aC = {0.f,0.f};          // a of current node
    int cur_n = 0, bound = 0, runk = 0;

    auto flush = [&]() {
        if (runk) {
            float fk = (float)runk;
            f32x2 fk2 = {fk, fk};
            smF += csrF; smC += csrC;
            smF = pk_fma2(fk2, aF, smF);
            smC = pk_fma2(fk2, aC, smC);
            f32x2 tF = pk_fma2(fk2, aF, csrF + csrF);   // k*a + 2*sum_c
            f32x2 tC = pk_fma2(fk2, aC, csrC + csrC);
            sqF = pk_fma2(aF, tF, sqF);
            sqC = pk_fma2(aC, tC, sqC);
        }
        csrF = (f32x2){0.f,0.f}; csrC = (f32x2){0.f,0.f};
        runk = 0;
    };
    auto loadA = [&](int n) {
        uint2 a8 = A16[(size_t)n * 64 + l];
        aF = (f32x2){bflo(a8.x), bfhi(a8.x)};
        aC = (f32x2){bflo(a8.y), bfhi(a8.y)};
    };

    if (e0 < e1) {
        cur_n = __builtin_amdgcn_readfirstlane(slots[slot]);
        bound = __builtin_amdgcn_readfirstlane(rowptr[cur_n + 1]);
        loadA(cur_n);
    }

    auto proc = [&](int e, unsigned p) {
        if (e >= bound) {                            // scalar branch (e, bound in SGPR)
            flush();
            do { cur_n++; bound = __builtin_amdgcn_readfirstlane(rowptr[cur_n + 1]); } while (bound <= e);
            loadA(cur_n);
        }
        f32x2 vf, vc;
        fp8pair(p, vf, vc);
        csrF += vf; csrC += vc;
        sqF = pk_fma2(vf, vf, sqF);
        sqC = pk_fma2(vc, vc, sqC);
        runk++;
    };

    const int nfull = (e1 - e0) & ~7;                // e0 is 8-aligned (per_slot % 8 == 0)
    if (nfull > 0) {
        int eg = e0;
        unsigned cur[8];
        {
            int4 m0 = *(const int4*)(sidx1 + eg);
            int4 m1 = *(const int4*)(sidx1 + eg + 4);
            cur[0] = *(const unsigned*)(Cp8b + ((unsigned)m0.x + lo4));
            cur[1] = *(const unsigned*)(Cp8b + ((unsigned)m0.y + lo4));
            cur[2] = *(const unsigned*)(Cp8b + ((unsigned)m0.z + lo4));
            cur[3] = *(const unsigned*)(Cp8b + ((unsigned)m0.w + lo4));
            cur[4] = *(const unsigned*)(Cp8b + ((unsigned)m1.x + lo4));
            cur[5] = *(const unsigned*)(Cp8b + ((unsigned)m1.y + lo4));
            cur[6] = *(const unsigned*)(Cp8b + ((unsigned)m1.z + lo4));
            cur[7] = *(const unsigned*)(Cp8b + ((unsigned)m1.w + lo4));
        }
        for (;;) {
            const int en = eg + 8;
            const bool more = en < e0 + nfull;
            unsigned nxt[8];
            if (more) {
                int4 t0 = *(const int4*)(sidx1 + en);
                int4 t1 = *(const int4*)(sidx1 + en + 4);
                nxt[0] = *(const unsigned*)(Cp8b + ((unsigned)t0.x + lo4));
                nxt[1] = *(const unsigned*)(Cp8b + ((unsigned)t0.y + lo4));
                nxt[2] = *(const unsigned*)(Cp8b + ((unsigned)t0.z + lo4));
                nxt[3] = *(const unsigned*)(Cp8b + ((unsigned)t0.w + lo4));
                nxt[4] = *(const unsigned*)(Cp8b + ((unsigned)t1.x + lo4));
                nxt[5] = *(const unsigned*)(Cp8b + ((unsigned)t1.y + lo4));
                nxt[6] = *(const unsigned*)(Cp8b + ((unsigned)t1.z + lo4));
                nxt[7] = *(const unsigned*)(Cp8b + ((unsigned)t1.w + lo4));
            }
            proc(eg, cur[0]);     proc(eg + 1, cur[1]);
            proc(eg + 2, cur[2]); proc(eg + 3, cur[3]);
            proc(eg + 4, cur[4]); proc(eg + 5, cur[5]);
            proc(eg + 6, cur[6]); proc(eg + 7, cur[7]);
            if (!more) break;
#pragma unroll
            for (int i = 0; i < 8; i++) cur[i] = nxt[i];
            eg = en;
        }
    }
    for (int e = e0 + nfull; e < e1; e++)
        proc(e, *(const unsigned*)(Cp8b + ((unsigned)sidx1[e] + lo4)));
    flush();

    lsm4[t] = (float4){smF.x, smF.y, smC.x, smC.y};
    lsq4[t] = (float4){sqF.x, sqF.y, sqC.x, sqC.y};
    __syncthreads();
    const float* fm = (const float*)lsm4;
    const float* fq = (const float*)lsq4;
    float vs = fm[t] + fm[256 + t] + fm[512 + t] + fm[768 + t];
    float vq = fq[t] + fq[256 + t] + fq[512 + t] + fq[768 + t];
    atomicAdd(&gsum[t], vs);
    atomicAdd(&gsq[t], vq);
}

// ---------------- fused BN1-finalize + msg + segment softmax ----------------
__global__ __launch_bounds__(256) void k_aggr(const uint2* __restrict__ A16, const unsigned char* __restrict__ Cp8b,
                                              const int* __restrict__ rowptr, const int* __restrict__ sidx1,
                                              const int* __restrict__ pos_of,
                                              const float* __restrict__ bn1_sum, const float* __restrict__ bn1_sq,
                                              const float* __restrict__ g1, const float* __restrict__ b1,
                                              const float* __restrict__ tptr, unsigned* __restrict__ out,
                                              float invE, int N) {
    const int t = threadIdx.x;
    const int l = t & 63;
    const int wid = __builtin_amdgcn_readfirstlane(t >> 6);
    const int n = blockIdx.x * 4 + wid;
    if (n >= N) return;

    const int e0 = __builtin_amdgcn_readfirstlane(rowptr[n]);
    const int e1 = __builtin_amdgcn_readfirstlane(rowptr[n + 1]);
    const int pn = __builtin_amdgcn_readfirstlane(pos_of[n]);

    const float tt = tptr[0];
    const float4 sum4 = ((const float4*)bn1_sum)[l];
    const float4 sq4  = ((const float4*)bn1_sq)[l];
    const float2 gf = ((const float2*)g1)[l];
    const float2 gc = ((const float2*)(g1 + 128))[l];
    const float2 bf2 = ((const float2*)b1)[l];
    const float2 bc2 = ((const float2*)(b1 + 128))[l];
    auto mkss = [&](float sum, float sq, float gg, float bb, float& sc, float& sh) {
        float mu = sum * invE;
        float var = sq * invE - mu * mu;
        sc = gg * rsqrtf(var + EPS_BN);
        sh = fmaf(-mu, sc, bb);
    };
    float scx, shx, scy, shy, scz, shz, scw, shw;
    mkss(sum4.x, sq4.x, gf.x, bf2.x, scx, shx);
    mkss(sum4.y, sq4.y, gf.y, bf2.y, scy, shy);
    mkss(sum4.z, sq4.z, gc.x, bc2.x, scz, shz);
    mkss(sum4.w, sq4.w, gc.y, bc2.y, scw, shw);
    const f32x2 sF  = {-scx * LOG2E, -scy * LOG2E};
    const f32x2 sC  = { scz * LOG2E,  scw * LOG2E};

    uint2 a8 = A16[(size_t)n * 64 + l];
    f32x2 aF = {bflo(a8.x), bfhi(a8.x)}, aC = {bflo(a8.y), bfhi(a8.y)};
    const f32x2 bF = pk_fma2(aF, sF, (f32x2){-shx * LOG2E, -shy * LOG2E});
    const f32x2 bC = pk_fma2(aC, sC, (f32x2){ shz * LOG2E,  shw * LOG2E});

    if (e0 >= e1) { out[(size_t)pn * 64 + l] = 0u; return; }

    const unsigned lo4 = (unsigned)(l << 2);
    f32x2 den = {0.f,0.f}, num = {0.f,0.f};

    auto G = [&](int e) -> unsigned {
        return *(const unsigned*)(Cp8b + ((unsigned)sidx1[e] + lo4));
    };
    auto procg = [&](unsigned p) {
        f32x2 vf, vc;
        fp8pair(p, vf, vc);
        f32x2 argf = pk_fma2(vf, sF, bF);            // -zf_hat * log2e
        f32x2 argc = pk_fma2(vc, sC, bC);            //  zc_hat * log2e
        f32x2 ef = {fexp2(argf.x), fexp2(argf.y)};
        f32x2 uu = {fexp2(argc.x), fexp2(argc.y)};
        f32x2 d1 = ef + 1.f;
        f32x2 u1 = uu + 1.f;
        f32x2 sig = {__builtin_amdgcn_rcpf(d1.x), __builtin_amdgcn_rcpf(d1.y)};
        f32x2 lg = {flog2(u1.x), flog2(u1.y)};
        f32x2 M = sig * lg;
        f32x2 tM = M * tt;
        f32x2 w = {fexp2(tM.x), fexp2(tM.y)};
        den += w;
        num = pk_fma2(M, w, num);
    };

    const int cnt = e1 - e0;                         // scalar
    unsigned cur[8];
#pragma unroll
    for (int i = 0; i < 8; i++)
        if (i < cnt) cur[i] = G(e0 + i);             // scalar-guarded loads

    int e = e0;
    while (e + 8 < e1) {                             // full group of 8 present
        unsigned nxt[8];
#pragma unroll
        for (int i = 0; i < 8; i++)
            if (e + 8 + i < e1) nxt[i] = G(e + 8 + i);   // scalar-guarded prefetch
#pragma unroll
        for (int i = 0; i < 8; i++) procg(cur[i]);
#pragma unroll
        for (int i = 0; i < 8; i++) cur[i] = nxt[i];
        e += 8;
    }
    const int rem = e1 - e;                          // 1..8, scalar
#pragma unroll
    for (int i = 0; i < 8; i++)
        if (i < rem) procg(cur[i]);                  // scalar-branch tail

    float ox = LN2 * num.x * __builtin_amdgcn_rcpf(den.x);
    float oy = LN2 * num.y * __builtin_amdgcn_rcpf(den.y);
    out[(size_t)pn * 64 + l] = pack2bf(ox, oy);
}

// ---------------- BN2 stats (packed-word loads + LDS reduce; order-agnostic) ----------------
__global__ __launch_bounds__(256) void k_bn2stats(const unsigned* __restrict__ outw, float* __restrict__ sum,
                                                  float* __restrict__ sq, int N) {
    __shared__ float4 ls[256];
    const int t = threadIdx.x;
    const int w = t & 63;
    const int rg = t >> 6;
    f32x2 sm = {0.f,0.f}, s2 = {0.f,0.f};
    for (int n = blockIdx.x * 4 + rg; n < N; n += gridDim.x * 4) {
        unsigned v = outw[(size_t)n * 64 + w];
        f32x2 x = {bflo(v), bfhi(v)};
        sm += x;
        s2 = pk_fma2(x, x, s2);
    }
    ls[t] = (float4){sm.x, sm.y, s2.x, s2.y};
    __syncthreads();
    if (t < 64) {
        float4 a = ls[t], b = ls[t + 64], c = ls[t + 128], d = ls[t + 192];
        atomicAdd(&sum[2 * w],     a.x + b.x + c.x + d.x);
        atomicAdd(&sum[2 * w + 1], a.y + b.y + c.y + d.y);
        atomicAdd(&sq[2 * w],      a.z + b.z + c.z + d.z);
        atomicAdd(&sq[2 * w + 1],  a.w + b.w + c.w + d.w);
    }
}

// ---------------- fused BN2-finalize + residual+softplus + mean-pool (dense, pooling order) ----------------
template<int SPLIT>
__global__ __launch_bounds__(128) void k_h2pool(const unsigned short* __restrict__ out,
                                                const unsigned short* __restrict__ h,
                                                const int* __restrict__ gptr,
                                                const float* __restrict__ bn2_sum, const float* __restrict__ bn2_sq,
                                                const float* __restrict__ g2, const float* __restrict__ b2,
                                                float* __restrict__ pooled, float invN) {
    const int g = blockIdx.x & 127;
    const int sp = blockIdx.x >> 7;
    const int c = threadIdx.x;
    float mu = bn2_sum[c] * invN;
    float var = bn2_sq[c] * invN - mu * mu;
    float sc = g2[c] * rsqrtf(var + EPS_BN);
    float sh = fmaf(-mu, sc, b2[c]);
    const int i0 = gptr[g], i1 = gptr[g + 1];
    float acc = 0.f;
    for (int i = i0 + sp; i < i1; i += SPLIT) {
        float v = fmaf(bfu16(out[(size_t)i * 128 + c]), sc, sh) + bfu16(h[(size_t)i * 128 + c]);
        acc += softplus_fast(v);
    }
    if (acc != 0.f) atomicAdd(&pooled[g * 128 + c], acc);
}

// ---------------- head ----------------
__global__ __launch_bounds__(256) void k_head(const float* __restrict__ pooled, const int* __restrict__ gcount,
                                              const float* __restrict__ l1w, const float* __restrict__ l1b,
                                              const float* __restrict__ outw, const float* __restrict__ outb,
                                              float* __restrict__ dout) {
    __shared__ float p[128];
    __shared__ float red[256];
    const int g = blockIdx.x;
    const int j = threadIdx.x;
    if (j < 128) {
        float cnt = (float)max(gcount[g], 1);
        p[j] = pooled[g * 128 + j] / cnt;
    }
    __syncthreads();
    float acc = l1b[j];
    for (int k = 0; k < 128; k++) acc = fmaf(p[k], l1w[k * 256 + j], acc);
    red[j] = softplus_fast(acc) * outw[j];
    __syncthreads();
    for (int s = 128; s > 0; s >>= 1) {
        if (j < s) red[j] += red[j + s];
        __syncthreads();
    }
    if (j == 0) dout[g] = red[0] + outb[0];
}

// ---------------- launch ----------------
extern "C" void kernel_launch(void* const* d_in, const int* in_sizes, int n_in,
                              void* d_out, int out_size, void* d_ws, size_t ws_size,
                              hipStream_t stream) {
    const float* x        = (const float*)d_in[0];
    const float* hedge    = (const float*)d_in[1];
    const int*   iri      = (const int*)d_in[2];
    const int*   batch    = (const int*)d_in[3];
    const float* embed_w  = (const float*)d_in[5];
    const float* embed_b  = (const float*)d_in[6];
    const float* bembed_w = (const float*)d_in[7];
    const float* bembed_b = (const float*)d_in[8];
    const float* lin_w    = (const float*)d_in[9];
    const float* lin_b    = (const float*)d_in[10];
    const float* bn1_g    = (const float*)d_in[11];
    const float* bn1_b    = (const float*)d_in[12];
    const float* bn2_g    = (const float*)d_in[13];
    const float* bn2_b    = (const float*)d_in[14];
    const float* aggr_t   = (const float*)d_in[15];
    const float* l1_w     = (const float*)d_in[16];
    const float* l1_b     = (const float*)d_in[17];
    const float* out_w    = (const float*)d_in[18];
    const float* out_b    = (const float*)d_in[19];

    const int N   = in_sizes[0] / 92;
    const int NHE = in_sizes[1] / 40;
    const int E   = in_sizes[2] / 3;
    const int* idx0 = iri;
    const int* idx1 = iri + E;

    float* ws = (float*)d_ws;
    size_t off = 0;
    auto alloc = [&](size_t elems) -> float* {
        float* p = ws + off;
        off += (elems + 63) & ~(size_t)63;
        return p;
    };
    unsigned short* h16 = (unsigned short*)alloc((size_t)N * 64);   // N*128 bf16 (pooling order)
    uint2* A16    = (uint2*)alloc((size_t)N * 128);                 // N*256 bf16 packed
    unsigned* Cp8 = (unsigned*)alloc((size_t)NHE * 64);             // NHE*256 fp8 packed
    unsigned short* embB  = (unsigned short*)alloc(6144);
    unsigned short* bembB = (unsigned short*)alloc(4096);
    unsigned short* waB   = (unsigned short*)alloc(16384);
    unsigned short* wcB   = (unsigned short*)alloc(16384);
    int*   rowptr = (int*)alloc((size_t)N + 1);
    int*   boff   = (int*)alloc(260);
    int*   sidx1  = (int*)alloc((size_t)E + 8);
    int*   staging = (int*)alloc((size_t)E + 8);
    int*   gptr   = (int*)alloc(129);
    int*   pos_of = (int*)alloc((size_t)N);
    int*   slots  = (int*)alloc(8200);
    unsigned* outbuf = (unsigned*)alloc((size_t)N * 64);            // N*128 bf16 (pooling order)
    // contiguous zero region
    float* zbase  = ws + off;
    int*   bsum   = (int*)alloc(256);
    int*   bfill  = (int*)alloc(256);
    int*   gfill  = (int*)alloc(128);
    int*   gcount = (int*)alloc(128);
    float* bn1_sum = alloc(256);
    float* bn1_sq  = alloc(256);
    float* bn2_sum = alloc(128);
    float* bn2_sq  = alloc(128);
    float* pooled  = alloc(128 * 128);
    size_t zbytes = (size_t)((ws + off) - zbase) * sizeof(float);
    (void)ws_size;  // ~81MB; fit verified

    hipMemsetAsync(zbase, 0, zbytes, stream);

    const int NB = (N + 255) >> BIN_SH;
    const int EB = (E + BIN_CHUNK - 1) / BIN_CHUNK;
    const int GB = (N + 255) / 256;

    // weight prep + counts (merged)
    k_pre<<<320 + EB, 256, 0, stream>>>(embed_w, bembed_w, lin_w, embB, bembB, waB, wcB,
                                        idx0, batch, bsum, gcount, E, N, NB);

    // scans + scatterpos (merged; scatterpos computes gptr locally)
    k_scan<<<1 + GB, 256, 0, stream>>>(bsum, boff, gcount, gptr, batch, gfill, pos_of, N, NB);

    // GEMM1 + GEMM2 + binA (merged block ranges)
    const int mtN   = (N + 31) / 32;
    const int mtNHE = (NHE + 31) / 32;
    k_main<<<mtN + mtNHE + EB, 256, 0, stream>>>(
        x, embB, embed_b, waB, lin_b, h16, A16, N, pos_of,
        hedge, bembB, bembed_b, wcB, Cp8, NHE,
        idx0, idx1, boff, bfill, staging, E, NB, mtN, mtNHE);

    // binB: two-pass bucket -> {rowptr, CSR} + slot table
    const int EDGE_BLOCKS = 2048;
    const int NSLOTS = EDGE_BLOCKS * 4;
    int per_slot = ((E + NSLOTS - 1) / NSLOTS + 7) & ~7;
    k_binB<<<NB, 256, 0, stream>>>(boff, staging, rowptr, sidx1, slots, E, N, per_slot);

    // BN1 stats: full z moments in one edge pass (slot-start)
    k_stats<<<EDGE_BLOCKS, 256, 0, stream>>>(A16, (const unsigned char*)Cp8, rowptr, sidx1, slots,
                                             bn1_sum, bn1_sq, E, N, per_slot);

    // fused BN1-finalize + message + softmax aggregation (out in pooling order)
    k_aggr<<<(N + 3) / 4, 256, 0, stream>>>(A16, (const unsigned char*)Cp8, rowptr, sidx1, pos_of,
                                            bn1_sum, bn1_sq, bn1_g, bn1_b, aggr_t, outbuf,
                                            1.0f / (float)E, N);

    // BN2 stats + fused finalize/residual/softplus/pool (fully dense)
    k_bn2stats<<<256, 256, 0, stream>>>((const unsigned*)outbuf, bn2_sum, bn2_sq, N);
    k_h2pool<16><<<128 * 16, 128, 0, stream>>>((const unsigned short*)outbuf, h16, gptr,
                                               bn2_sum, bn2_sq, bn2_g, bn2_b, pooled, 1.0f / (float)N);

    // head
    k_head<<<128, 256, 0, stream>>>(pooled, gcount, l1_w, l1_b, out_w, out_b, (float*)d_out);
}